// Round 7
// baseline (360.998 us; speedup 1.0000x reference)
//
#include <hip/hip_runtime.h>

typedef __bf16 bf16x8 __attribute__((ext_vector_type(8)));
typedef __bf16 bf16x4 __attribute__((ext_vector_type(4)));
typedef float f32x4 __attribute__((ext_vector_type(4)));

namespace {
constexpr int Bn = 2, Cn = 64, hn = 96, wn = 96, Hn = 384, Wn = 384;
constexpr int CIN = 266;
constexpr int TM = 64;                      // pixels per workgroup tile
constexpr int SP = 296;                     // Abuf row stride (bf16): 592B
// fragment-major weight layouts. A-frag mapping for mfma_f32_16x16x32_bf16:
// lane l supplies A[m = l&15][k = (l>>4)*8 + j].
constexpr int L1_FRAGS = 9 * 16 * 64;       // 9216
constexpr int L2_FRAGS = 8 * 16 * 64;       // 8192
constexpr int L3_FRAGS = 8 * 64;            // 512
constexpr int N_FRAGS = L1_FRAGS + L2_FRAGS + L3_FRAGS;   // 17920
constexpr int SC_OFF_BYTES = N_FRAGS * 16;                 // 286720
constexpr int B1EFF_OFF_BYTES = SC_OFF_BYTES + Bn * 3 * hn * wn * 4;
constexpr int FEATT_OFF_BYTES = B1EFF_OFF_BYTES + 1024;    // featT: [B][h][w][C] f32
constexpr int FRAG_BLOCKS = N_FRAGS / 256;  // 70
constexpr int SC_BLOCKS = (Bn * hn * wn) / 256;  // 72
}

// ---------------- prep (single dispatch): weight frags + b1eff + shortcut MLP + featT ----------------
__global__ void prep_all(const float* __restrict__ w00, const float* __restrict__ w1,
                         const float* __restrict__ w2, const float* __restrict__ b00,
                         const float* __restrict__ b1,
                         const float* __restrict__ feat, const float* __restrict__ ws1,
                         const float* __restrict__ bs1, const float* __restrict__ ws2,
                         const float* __restrict__ bs2,
                         __bf16* __restrict__ wb, float* __restrict__ b1eff,
                         float* __restrict__ sc, float* __restrict__ featT)
{
    const int bid = blockIdx.x;
    if (bid < FRAG_BLOCKS) {
        const int f = bid * 256 + threadIdx.x;
        bf16x8 v;
        if (f < L1_FRAGS) {
            const int k0 = f >> 10;
            const int mb = (f >> 6) & 15;
            const int l  = f & 63;
            const int m  = mb * 16 + (l & 15);
            const int kb = k0 * 32 + (l >> 4) * 8;
#pragma unroll
            for (int j = 0; j < 8; j++)
                v[j] = (kb + j < CIN) ? (__bf16)w00[m * CIN + kb + j] : (__bf16)0.f;
        } else if (f < L1_FRAGS + L2_FRAGS) {
            const int g = f - L1_FRAGS;
            const int k0 = g >> 10;
            const int mb = (g >> 6) & 15;
            const int l  = g & 63;
            const int m  = mb * 16 + (l & 15);
            const int kb = k0 * 32 + (l >> 4) * 8;
#pragma unroll
            for (int j = 0; j < 8; j++) v[j] = (__bf16)w1[m * 256 + kb + j];
        } else {
            const int g = f - (L1_FRAGS + L2_FRAGS);
            const int k0 = g >> 6;
            const int l  = g & 63;
            const int m  = l & 15;
            const int kb = k0 * 32 + (l >> 4) * 8;
#pragma unroll
            for (int j = 0; j < 8; j++)
                v[j] = (m < 3) ? (__bf16)w2[m * 256 + kb + j] : (__bf16)0.f;
        }
        *(bf16x8*)(wb + f * 8) = v;
        return;
    }
    if (bid == FRAG_BLOCKS) {
        // b1eff[o] = b1[o] + sum_c w1[o][c]*(b00[c] + 0.5*(w00[c][264]+w00[c][265]))
        __shared__ float cb[256];
        const int o = threadIdx.x;
        cb[o] = b00[o] + 0.5f * (w00[o * CIN + 264] + w00[o * CIN + 265]);
        __syncthreads();
        float v = b1[o];
#pragma unroll 4
        for (int k = 0; k < 256; k++) v = fmaf(w1[o * 256 + k], cb[k], v);
        b1eff[o] = v;
        return;
    }
    // shortcut MLP on LR grid; also emits the channel-last featT for the main gather
    const int t = (bid - FRAG_BLOCKS - 1) * 256 + threadIdx.x;
    if (t >= Bn * hn * wn) return;
    const int b = t / (hn * wn);
    const int yx = t % (hn * wn);
    const float* fp = feat + b * Cn * hn * wn + yx;
    float f[Cn];
#pragma unroll
    for (int c = 0; c < Cn; c++) f[c] = fp[c * hn * wn];
    // featT[b][y][x][c] = feat[b][c][y][x]  (t*64 is exactly ((b*h+y)*w+x)*64)
    {
        float* ft = featT + t * Cn;
#pragma unroll
        for (int c4 = 0; c4 < Cn / 4; c4++)
            *(f32x4*)&ft[c4 * 4] =
                (f32x4){f[4 * c4], f[4 * c4 + 1], f[4 * c4 + 2], f[4 * c4 + 3]};
    }
    float o0 = bs2[0], o1 = bs2[1], o2 = bs2[2];
#pragma unroll 1
    for (int co = 0; co < Cn; co += 4) {
        float v0 = bs1[co], v1 = bs1[co + 1], v2 = bs1[co + 2], v3 = bs1[co + 3];
        const float* wr = ws1 + co * Cn;
#pragma unroll
        for (int ci = 0; ci < Cn; ci++) {
            const float fv = f[ci];
            v0 = fmaf(wr[ci], fv, v0);
            v1 = fmaf(wr[Cn + ci], fv, v1);
            v2 = fmaf(wr[2 * Cn + ci], fv, v2);
            v3 = fmaf(wr[3 * Cn + ci], fv, v3);
        }
        v0 = fmaxf(v0, 0.f); v1 = fmaxf(v1, 0.f); v2 = fmaxf(v2, 0.f); v3 = fmaxf(v3, 0.f);
#pragma unroll
        for (int u = 0; u < 4; u++) {
            const float vv = (u == 0) ? v0 : (u == 1) ? v1 : (u == 2) ? v2 : v3;
            o0 = fmaf(ws2[co + u], vv, o0);
            o1 = fmaf(ws2[Cn + co + u], vv, o1);
            o2 = fmaf(ws2[2 * Cn + co + u], vv, o2);
        }
    }
    sc[(b * 3 + 0) * hn * wn + yx] = o0;
    sc[(b * 3 + 1) * hn * wn + yx] = o1;
    sc[(b * 3 + 2) * hn * wn + yx] = o2;
}

__device__ __forceinline__ float gelu_fast(float x) {
    // tanh-form gelu via sigmoid in exp2 domain: x * 1/(1 + 2^(x*(d0+d1*x^2)))
    const float d0 = -2.302118074f;   // -2*0.7978845608*log2(e)
    const float d1 = -0.1029453754f;  // -2*0.0356774081*log2(e)
    float t = x * x;
    float a = x * fmaf(t, d1, d0);
    float e = __builtin_amdgcn_exp2f(a);
    return x * __builtin_amdgcn_rcpf(1.f + e);
}

__device__ __forceinline__ bf16x4 pack4(f32x4 x) {
    bf16x4 v;
    v[0] = (__bf16)x[0]; v[1] = (__bf16)x[1]; v[2] = (__bf16)x[2]; v[3] = (__bf16)x[3];
    return v;
}

// ---------------- fused main kernel ----------------
// Operand-swapped GEMMs: D = W (A-operand, global->VGPR stream) x Act^T
// (B-operand from LDS). Hot path fully scalarized (array indirection on the
// weight double-buffer defeats mem2reg -> scratch spill -> HBM blowup).
// Locked-in lessons: 16x16x32 MFMA (R1); no VGPR<=64 restructure (R3/R4 spill);
// no s_setprio (R5, +9us). R7: 2-tile persistent blocks (grid 4608->2304) with
// T14 async stage: tile-B's 16 feat loads issue after tile-A's gelu epilogue
// (wdbuf dead, acc draining) and their latency hides under A's L3+out; B's
// coords compute in the shadow of A's L1 MFMAs. B starts its GEMMs with no
// serial gather phase. Spill tripwire: FETCH_SIZE must stay ~3.8MB.

#define MF(A, B, C) __builtin_amdgcn_mfma_f32_16x16x32_bf16((A), (B), (C), 0, 0, 0)

// 16 MFMAs of one kstep: weights W0..W3 (mblocks mb0..mb0+3) x 4 pixel-blocks
#define GSTEP(k0, W0, W1, W2, W3) do {                                          \
    const bf16x8 g0 = *(const bf16x8*)&Abuf[     lane16][(k0) * 32 + quad * 8]; \
    const bf16x8 g1 = *(const bf16x8*)&Abuf[16 + lane16][(k0) * 32 + quad * 8]; \
    const bf16x8 g2 = *(const bf16x8*)&Abuf[32 + lane16][(k0) * 32 + quad * 8]; \
    const bf16x8 g3 = *(const bf16x8*)&Abuf[48 + lane16][(k0) * 32 + quad * 8]; \
    a00 = MF(W0, g0, a00); a01 = MF(W1, g0, a01); a02 = MF(W2, g0, a02); a03 = MF(W3, g0, a03); \
    a10 = MF(W0, g1, a10); a11 = MF(W1, g1, a11); a12 = MF(W2, g1, a12); a13 = MF(W3, g1, a13); \
    a20 = MF(W0, g2, a20); a21 = MF(W1, g2, a21); a22 = MF(W2, g2, a22); a23 = MF(W3, g2, a23); \
    a30 = MF(W0, g3, a30); a31 = MF(W1, g3, a31); a32 = MF(W2, g3, a32); a33 = MF(W3, g3, a33); \
} while (0)

#define LDW(W0, W1, W2, W3, src, kk) do {             \
    W0 = (src)[((kk) * 16 + mb0 + 0) * 64 + lane];    \
    W1 = (src)[((kk) * 16 + mb0 + 1) * 64 + lane];    \
    W2 = (src)[((kk) * 16 + mb0 + 2) * 64 + lane];    \
    W3 = (src)[((kk) * 16 + mb0 + 3) * 64 + lane];    \
} while (0)

#define ZACCALL do { a00 = zf; a01 = zf; a02 = zf; a03 = zf; \
    a10 = zf; a11 = zf; a12 = zf; a13 = zf;                   \
    a20 = zf; a21 = zf; a22 = zf; a23 = zf;                   \
    a30 = zf; a31 = zf; a32 = zf; a33 = zf; } while (0)

// layer 1: 9 ksteps; ends with wf2 k0 in wO*, k1 in wE*
#define L1_SEC do {                                                   \
    GSTEP(0, wE0, wE1, wE2, wE3); LDW(wE0, wE1, wE2, wE3, wf1, 2);    \
    GSTEP(1, wO0, wO1, wO2, wO3); LDW(wO0, wO1, wO2, wO3, wf1, 3);    \
    GSTEP(2, wE0, wE1, wE2, wE3); LDW(wE0, wE1, wE2, wE3, wf1, 4);    \
    GSTEP(3, wO0, wO1, wO2, wO3); LDW(wO0, wO1, wO2, wO3, wf1, 5);    \
    GSTEP(4, wE0, wE1, wE2, wE3); LDW(wE0, wE1, wE2, wE3, wf1, 6);    \
    GSTEP(5, wO0, wO1, wO2, wO3); LDW(wO0, wO1, wO2, wO3, wf1, 7);    \
    GSTEP(6, wE0, wE1, wE2, wE3); LDW(wE0, wE1, wE2, wE3, wf1, 8);    \
    GSTEP(7, wO0, wO1, wO2, wO3); LDW(wO0, wO1, wO2, wO3, wf2, 0);    \
    GSTEP(8, wE0, wE1, wE2, wE3); LDW(wE0, wE1, wE2, wE3, wf2, 1);    \
} while (0)

// layer 2: 8 ksteps (k0 in wO, k1 in wE); ends with w2f[0] in wO0, w2f[1] in wE0
#define L2_SEC do {                                                   \
    GSTEP(0, wO0, wO1, wO2, wO3); LDW(wO0, wO1, wO2, wO3, wf2, 2);    \
    GSTEP(1, wE0, wE1, wE2, wE3); LDW(wE0, wE1, wE2, wE3, wf2, 3);    \
    GSTEP(2, wO0, wO1, wO2, wO3); LDW(wO0, wO1, wO2, wO3, wf2, 4);    \
    GSTEP(3, wE0, wE1, wE2, wE3); LDW(wE0, wE1, wE2, wE3, wf2, 5);    \
    GSTEP(4, wO0, wO1, wO2, wO3); LDW(wO0, wO1, wO2, wO3, wf2, 6);    \
    GSTEP(5, wE0, wE1, wE2, wE3); LDW(wE0, wE1, wE2, wE3, wf2, 7);    \
    GSTEP(6, wO0, wO1, wO2, wO3); wO0 = w2f[0 * 64 + lane];           \
    GSTEP(7, wE0, wE1, wE2, wE3); wE0 = w2f[1 * 64 + lane];           \
} while (0)

#define YF(k0) (*(const bf16x8*)&Abuf[wv * 16 + lane16][(k0) * 32 + quad * 8])
#define L3_SEC do {                                                   \
    acc3 = zf;                                                        \
    acc3 = MF(wO0, YF(0), acc3); wO0 = w2f[2 * 64 + lane];            \
    acc3 = MF(wE0, YF(1), acc3); wE0 = w2f[3 * 64 + lane];            \
    acc3 = MF(wO0, YF(2), acc3); wO0 = w2f[4 * 64 + lane];            \
    acc3 = MF(wE0, YF(3), acc3); wE0 = w2f[5 * 64 + lane];            \
    acc3 = MF(wO0, YF(4), acc3); wO0 = w2f[6 * 64 + lane];            \
    acc3 = MF(wE0, YF(5), acc3); wE0 = w2f[7 * 64 + lane];            \
    acc3 = MF(wO0, YF(6), acc3);                                      \
    acc3 = MF(wE0, YF(7), acc3);                                      \
} while (0)

// epilogue 1: no bias (b00 + rel_cell folded into b1eff); packed b64 writes
#define EP1_STORE do {                                                \
    const int ch0 = mb0 * 16 + quad * 4;                              \
    *(bf16x4*)&Abuf[     lane16][ch0     ] = pack4(a00);              \
    *(bf16x4*)&Abuf[16 + lane16][ch0     ] = pack4(a10);              \
    *(bf16x4*)&Abuf[32 + lane16][ch0     ] = pack4(a20);              \
    *(bf16x4*)&Abuf[48 + lane16][ch0     ] = pack4(a30);              \
    *(bf16x4*)&Abuf[     lane16][ch0 + 16] = pack4(a01);              \
    *(bf16x4*)&Abuf[16 + lane16][ch0 + 16] = pack4(a11);              \
    *(bf16x4*)&Abuf[32 + lane16][ch0 + 16] = pack4(a21);              \
    *(bf16x4*)&Abuf[48 + lane16][ch0 + 16] = pack4(a31);              \
    *(bf16x4*)&Abuf[     lane16][ch0 + 32] = pack4(a02);              \
    *(bf16x4*)&Abuf[16 + lane16][ch0 + 32] = pack4(a12);              \
    *(bf16x4*)&Abuf[32 + lane16][ch0 + 32] = pack4(a22);              \
    *(bf16x4*)&Abuf[48 + lane16][ch0 + 32] = pack4(a32);              \
    *(bf16x4*)&Abuf[     lane16][ch0 + 48] = pack4(a03);              \
    *(bf16x4*)&Abuf[16 + lane16][ch0 + 48] = pack4(a13);              \
    *(bf16x4*)&Abuf[32 + lane16][ch0 + 48] = pack4(a23);              \
    *(bf16x4*)&Abuf[48 + lane16][ch0 + 48] = pack4(a33);              \
} while (0)

#define GEL4(x, bi) { bf16x4 v_; v_[0] = (__bf16)gelu_fast((x)[0] + (bi)[0]); \
    v_[1] = (__bf16)gelu_fast((x)[1] + (bi)[1]); \
    v_[2] = (__bf16)gelu_fast((x)[2] + (bi)[2]); \
    v_[3] = (__bf16)gelu_fast((x)[3] + (bi)[3]); vv = v_; }

// epilogue 2: bias + gelu, packed b64 writes
#define EP2_STORE do {                                                \
    const int ch0 = mb0 * 16 + quad * 4;                              \
    const f32x4 bi0 = *(const f32x4*)&b1eff[ch0];                     \
    const f32x4 bi1 = *(const f32x4*)&b1eff[ch0 + 16];                \
    const f32x4 bi2 = *(const f32x4*)&b1eff[ch0 + 32];                \
    const f32x4 bi3 = *(const f32x4*)&b1eff[ch0 + 48];                \
    bf16x4 vv;                                                        \
    GEL4(a00, bi0); *(bf16x4*)&Abuf[     lane16][ch0     ] = vv;      \
    GEL4(a10, bi0); *(bf16x4*)&Abuf[16 + lane16][ch0     ] = vv;      \
    GEL4(a20, bi0); *(bf16x4*)&Abuf[32 + lane16][ch0     ] = vv;      \
    GEL4(a30, bi0); *(bf16x4*)&Abuf[48 + lane16][ch0     ] = vv;      \
    GEL4(a01, bi1); *(bf16x4*)&Abuf[     lane16][ch0 + 16] = vv;      \
    GEL4(a11, bi1); *(bf16x4*)&Abuf[16 + lane16][ch0 + 16] = vv;      \
    GEL4(a21, bi1); *(bf16x4*)&Abuf[32 + lane16][ch0 + 16] = vv;      \
    GEL4(a31, bi1); *(bf16x4*)&Abuf[48 + lane16][ch0 + 16] = vv;      \
    GEL4(a02, bi2); *(bf16x4*)&Abuf[     lane16][ch0 + 32] = vv;      \
    GEL4(a12, bi2); *(bf16x4*)&Abuf[16 + lane16][ch0 + 32] = vv;      \
    GEL4(a22, bi2); *(bf16x4*)&Abuf[32 + lane16][ch0 + 32] = vv;      \
    GEL4(a32, bi2); *(bf16x4*)&Abuf[48 + lane16][ch0 + 32] = vv;      \
    GEL4(a03, bi3); *(bf16x4*)&Abuf[     lane16][ch0 + 48] = vv;      \
    GEL4(a13, bi3); *(bf16x4*)&Abuf[16 + lane16][ch0 + 48] = vv;      \
    GEL4(a23, bi3); *(bf16x4*)&Abuf[32 + lane16][ch0 + 48] = vv;      \
    GEL4(a33, bi3); *(bf16x4*)&Abuf[48 + lane16][ch0 + 48] = vv;      \
} while (0)

// final output epilogue (rows 0..2 / quad 0 hold the 3 output channels)
#define OUT_EPI(cy_, Y_, X0_, b_) do { if (quad == 0) {                              \
    const int pix = wv * 16 + lane16;                                                \
    const int X = (X0_) + pix;                                                       \
    const float uy = (((cy_) + 1.f) * hn - 1.f) * 0.5f;                              \
    const float fy = floorf(uy);                                                     \
    const float wy = uy - fy;                                                        \
    const int y0i = min(max((int)fy, 0), hn - 1);                                    \
    const int y1i = min(max((int)fy + 1, 0), hn - 1);                                \
    const float cx_ = -1.f + 1.f / Wn + (2.f / Wn) * (float)X;                       \
    const float ux = ((cx_ + 1.f) * wn - 1.f) * 0.5f;                                \
    const float fx = floorf(ux);                                                     \
    const float wx = ux - fx;                                                        \
    const int x0i = min(max((int)fx, 0), wn - 1);                                    \
    const int x1i = min(max((int)fx + 1, 0), wn - 1);                                \
    const float w00b = (1.f - wy) * (1.f - wx), w01b = (1.f - wy) * wx;              \
    const float w10b = wy * (1.f - wx), w11b = wy * wx;                              \
    _Pragma("unroll")                                                                \
    for (int r = 0; r < 3; r++) {                                                    \
        const float* scb = sc + ((b_) * 3 + r) * (hn * wn);                          \
        const float samp = scb[y0i * wn + x0i] * w00b + scb[y0i * wn + x1i] * w01b   \
                         + scb[y1i * wn + x0i] * w10b + scb[y1i * wn + x1i] * w11b;  \
        out[(((b_) * 3 + r) * Hn + (Y_)) * Wn + X] = acc3[r] + b2v[r] + samp;        \
    } } } while (0)

__global__ __launch_bounds__(256, 3) void liif_main(
    const float* __restrict__ featT, const float* __restrict__ b1eff,
    const float* __restrict__ b2v, const __bf16* __restrict__ wb,
    const float* __restrict__ sc, float* __restrict__ out)
{
    __shared__ __align__(16) __bf16 Abuf[TM][SP];

    const int t = threadIdx.x;
    const int wv = t >> 6;
    const int lane = t & 63;
    const int lane16 = lane & 15;
    const int quad = lane >> 4;
    const int mb0 = wv * 4;

    // XCD swizzle over the 2304 super-blocks; each handles tiles {2q, 2q+1}
    constexpr int NWG2 = Bn * Hn * (Wn / TM) / 2;   // 2304
    const int q = (blockIdx.x & 7) * (NWG2 / 8) + (blockIdx.x >> 3);
    constexpr int TPR = Wn / TM;  // 6 tiles per HR row
    const int ltA = q * 2, ltB = q * 2 + 1;
    const int txA = ltA % TPR;
    const int YA = (ltA / TPR) % Hn;
    const int bA = ltA / (TPR * Hn);
    const int X0A = txA * TM;
    const int txB = ltB % TPR;
    const int YB = (ltB / TPR) % Hn;
    const int bB = ltB / (TPR * Hn);
    const int X0B = txB * TM;

    const float cyA = -1.f + 1.f / Hn + (2.f / Hn) * (float)YA;
    const float cyB = -1.f + 1.f / Hn + (2.f / Hn) * (float)YB;

    const bf16x8* wf1 = (const bf16x8*)wb;
    const bf16x8* wf2 = wf1 + L1_FRAGS;
    const bf16x8* w2f = wf1 + (L1_FRAGS + L2_FRAGS);

    // layer-1 initial prefetch (ksteps 0,1) issued BEFORE the gather
    bf16x8 wE0, wE1, wE2, wE3, wO0, wO1, wO2, wO3;
    LDW(wE0, wE1, wE2, wE3, wf1, 0);
    LDW(wO0, wO1, wO2, wO3, wf1, 1);

    // ---------- tile A phase 1: build grid features [64 x 266] bf16 in Abuf ----------
    {
        const int p = lane;     // pixel in tile
        const int j = wv;       // this wave handles corner j's gather
        const int X = X0A + p;
        const float cx = -1.f + 1.f / Wn + (2.f / Wn) * (float)X;
        float relyv[2], relxv[2];
        int iyy[2], ixx[2];
#pragma unroll
        for (int c2 = 0; c2 < 2; c2++) {
            const float v = c2 ? 1.f : -1.f;
            float sy = fminf(fmaxf(cyA + v * (1.f / hn) + 1e-6f, -1.f + 1e-6f), 1.f - 1e-6f);
            float uy = ((sy + 1.f) * hn - 1.f) * 0.5f;
            int iy = min(max((int)rintf(uy), 0), hn - 1);   // round-half-even == jnp.round
            float oy = -1.f + 1.f / hn + (2.f / hn) * (float)iy;
            relyv[c2] = (cyA - oy) * hn; iyy[c2] = iy;
            float sx = fminf(fmaxf(cx + v * (1.f / wn) + 1e-6f, -1.f + 1e-6f), 1.f - 1e-6f);
            float ux = ((sx + 1.f) * wn - 1.f) * 0.5f;
            int ix = min(max((int)rintf(ux), 0), wn - 1);
            float ox = -1.f + 1.f / wn + (2.f / wn) * (float)ix;
            relxv[c2] = (cx - ox) * wn; ixx[c2] = ix;
        }
        float area[4];
#pragma unroll
        for (int c = 0; c < 4; c++)
            area[c] = fabsf(relyv[(c >> 1) & 1] * relxv[c & 1]) + 1e-9f;
        const float tot = area[0] + area[1] + area[2] + area[3];
        const float wj = area[3 - j] / tot;   // LIIF area swap 0<->3, 1<->2

        if (j == 0) {
            bf16x8 v;
#pragma unroll
            for (int c = 0; c < 4; c++) {
                v[2 * c] = (__bf16)relyv[(c >> 1) & 1];
                v[2 * c + 1] = (__bf16)relxv[c & 1];
            }
            *(bf16x8*)&Abuf[p][0] = v;
        }
        const float* fb = featT + ((bA * hn + iyy[(j >> 1) & 1]) * wn + ixx[j & 1]) * Cn;
#pragma unroll
        for (int c8 = 0; c8 < 8; c8++) {
            const f32x4 u0 = *(const f32x4*)&fb[c8 * 8];
            const f32x4 u1 = *(const f32x4*)&fb[c8 * 8 + 4];
            bf16x8 v;
            v[0] = (__bf16)(u0[0] * wj); v[1] = (__bf16)(u0[1] * wj);
            v[2] = (__bf16)(u0[2] * wj); v[3] = (__bf16)(u0[3] * wj);
            v[4] = (__bf16)(u1[0] * wj); v[5] = (__bf16)(u1[1] * wj);
            v[6] = (__bf16)(u1[2] * wj); v[7] = (__bf16)(u1[3] * wj);
            *(bf16x8*)&Abuf[p][8 + 64 * j + c8 * 8] = v;
        }
        if (j == 3) {
            bf16x8 z;
#pragma unroll
            for (int cc = 0; cc < 8; cc++) z[cc] = (__bf16)0.f;
            *(bf16x8*)&Abuf[p][264] = z;
            *(bf16x8*)&Abuf[p][272] = z;
            *(bf16x8*)&Abuf[p][280] = z;
        }
    }
    __syncthreads();

    const f32x4 zf = (f32x4){0.f, 0.f, 0.f, 0.f};
    f32x4 a00, a01, a02, a03, a10, a11, a12, a13;
    f32x4 a20, a21, a22, a23, a30, a31, a32, a33;
    f32x4 acc3;
    ZACCALL;

    // ---------- tile A layer 1 (tile-B coords computed in its MFMA shadow) ----------
    L1_SEC;

    // tile-B coords: kept in scalars until the B-store at the end of tile A
    float ryB0, ryB1, rxB0, rxB1, wjB;
    const float* fbB;
    {
        const float cx = -1.f + 1.f / Wn + (2.f / Wn) * (float)(X0B + lane);
        float relyv[2], relxv[2];
        int iyy[2], ixx[2];
#pragma unroll
        for (int c2 = 0; c2 < 2; c2++) {
            const float v = c2 ? 1.f : -1.f;
            float sy = fminf(fmaxf(cyB + v * (1.f / hn) + 1e-6f, -1.f + 1e-6f), 1.f - 1e-6f);
            float uy = ((sy + 1.f) * hn - 1.f) * 0.5f;
            int iy = min(max((int)rintf(uy), 0), hn - 1);
            float oy = -1.f + 1.f / hn + (2.f / hn) * (float)iy;
            relyv[c2] = (cyB - oy) * hn; iyy[c2] = iy;
            float sx = fminf(fmaxf(cx + v * (1.f / wn) + 1e-6f, -1.f + 1e-6f), 1.f - 1e-6f);
            float ux = ((sx + 1.f) * wn - 1.f) * 0.5f;
            int ix = min(max((int)rintf(ux), 0), wn - 1);
            float ox = -1.f + 1.f / wn + (2.f / wn) * (float)ix;
            relxv[c2] = (cx - ox) * wn; ixx[c2] = ix;
        }
        float area[4];
#pragma unroll
        for (int c = 0; c < 4; c++)
            area[c] = fabsf(relyv[(c >> 1) & 1] * relxv[c & 1]) + 1e-9f;
        const float tot = area[0] + area[1] + area[2] + area[3];
        wjB = area[3 - wv] / tot;
        ryB0 = relyv[0]; ryB1 = relyv[1]; rxB0 = relxv[0]; rxB1 = relxv[1];
        fbB = featT + ((bB * hn + iyy[(wv >> 1) & 1]) * wn + ixx[wv & 1]) * Cn;
    }

    __syncthreads();
    EP1_STORE;
    __syncthreads();

    ZACCALL;
    L2_SEC;

    __syncthreads();
    EP2_STORE;
    __syncthreads();

    // issue tile-B feat loads; latency hides under L3(A) + out(A)
    const f32x4 uB0  = *(const f32x4*)&fbB[0];
    const f32x4 uB1  = *(const f32x4*)&fbB[4];
    const f32x4 uB2  = *(const f32x4*)&fbB[8];
    const f32x4 uB3  = *(const f32x4*)&fbB[12];
    const f32x4 uB4  = *(const f32x4*)&fbB[16];
    const f32x4 uB5  = *(const f32x4*)&fbB[20];
    const f32x4 uB6  = *(const f32x4*)&fbB[24];
    const f32x4 uB7  = *(const f32x4*)&fbB[28];
    const f32x4 uB8  = *(const f32x4*)&fbB[32];
    const f32x4 uB9  = *(const f32x4*)&fbB[36];
    const f32x4 uB10 = *(const f32x4*)&fbB[40];
    const f32x4 uB11 = *(const f32x4*)&fbB[44];
    const f32x4 uB12 = *(const f32x4*)&fbB[48];
    const f32x4 uB13 = *(const f32x4*)&fbB[52];
    const f32x4 uB14 = *(const f32x4*)&fbB[56];
    const f32x4 uB15 = *(const f32x4*)&fbB[60];

    L3_SEC;
    // tile-B layer-1 weight prefetch (ksteps 0,1)
    LDW(wE0, wE1, wE2, wE3, wf1, 0);
    LDW(wO0, wO1, wO2, wO3, wf1, 1);
    OUT_EPI(cyA, YA, X0A, bA);
    __syncthreads();   // all L3(A) Abuf readers done before overwrite

    // ---------- tile B gather-store from registers ----------
    {
        if (wv == 0) {
            bf16x8 v;
            v[0] = (__bf16)ryB0; v[1] = (__bf16)rxB0;
            v[2] = (__bf16)ryB0; v[3] = (__bf16)rxB1;
            v[4] = (__bf16)ryB1; v[5] = (__bf16)rxB0;
            v[6] = (__bf16)ryB1; v[7] = (__bf16)rxB1;
            *(bf16x8*)&Abuf[lane][0] = v;
        }
#define STB(c8, U0, U1) { bf16x8 v;                                       \
        v[0] = (__bf16)((U0)[0] * wjB); v[1] = (__bf16)((U0)[1] * wjB);   \
        v[2] = (__bf16)((U0)[2] * wjB); v[3] = (__bf16)((U0)[3] * wjB);   \
        v[4] = (__bf16)((U1)[0] * wjB); v[5] = (__bf16)((U1)[1] * wjB);   \
        v[6] = (__bf16)((U1)[2] * wjB); v[7] = (__bf16)((U1)[3] * wjB);   \
        *(bf16x8*)&Abuf[lane][8 + 64 * wv + (c8) * 8] = v; }
        STB(0, uB0,  uB1);  STB(1, uB2,  uB3);
        STB(2, uB4,  uB5);  STB(3, uB6,  uB7);
        STB(4, uB8,  uB9);  STB(5, uB10, uB11);
        STB(6, uB12, uB13); STB(7, uB14, uB15);
#undef STB
        if (wv == 3) {
            bf16x8 z;
#pragma unroll
            for (int cc = 0; cc < 8; cc++) z[cc] = (__bf16)0.f;
            *(bf16x8*)&Abuf[lane][264] = z;
            *(bf16x8*)&Abuf[lane][272] = z;
            *(bf16x8*)&Abuf[lane][280] = z;
        }
    }
    __syncthreads();

    // ---------- tile B pipeline ----------
    ZACCALL;
    L1_SEC;
    __syncthreads();
    EP1_STORE;
    __syncthreads();
    ZACCALL;
    L2_SEC;
    __syncthreads();
    EP2_STORE;
    __syncthreads();
    L3_SEC;
    OUT_EPI(cyB, YB, X0B, bB);
}

extern "C" void kernel_launch(void* const* d_in, const int* in_sizes, int n_in,
                              void* d_out, int out_size, void* d_ws, size_t ws_size,
                              hipStream_t stream)
{
    const float* feat = (const float*)d_in[0];
    const float* w00  = (const float*)d_in[1];
    const float* b00  = (const float*)d_in[2];
    const float* w1   = (const float*)d_in[3];
    const float* b1   = (const float*)d_in[4];
    const float* w2   = (const float*)d_in[5];
    const float* b2   = (const float*)d_in[6];
    const float* ws1  = (const float*)d_in[7];
    const float* bs1  = (const float*)d_in[8];
    const float* ws2  = (const float*)d_in[9];
    const float* bs2  = (const float*)d_in[10];
    float* out = (float*)d_out;

    __bf16* wb    = (__bf16*)d_ws;
    float* scbuf  = (float*)((char*)d_ws + SC_OFF_BYTES);
    float* b1eff  = (float*)((char*)d_ws + B1EFF_OFF_BYTES);
    float* featT  = (float*)((char*)d_ws + FEATT_OFF_BYTES);

    prep_all<<<FRAG_BLOCKS + 1 + SC_BLOCKS, 256, 0, stream>>>(
        w00, w1, w2, b00, b1, feat, ws1, bs1, ws2, bs2, wb, b1eff, scbuf, featT);
    liif_main<<<Bn * Hn * (Wn / TM) / 2, 256, 0, stream>>>(featT, b1eff, b2, wb, scbuf, out);
}

// Round 8
// 200.260 us; speedup vs baseline: 1.8026x; 1.8026x over previous
//
#include <hip/hip_runtime.h>

typedef __bf16 bf16x8 __attribute__((ext_vector_type(8)));
typedef __bf16 bf16x4 __attribute__((ext_vector_type(4)));
typedef float f32x4 __attribute__((ext_vector_type(4)));

namespace {
constexpr int Bn = 2, Cn = 64, hn = 96, wn = 96, Hn = 384, Wn = 384;
constexpr int CIN = 266;
constexpr int TM = 64;                      // pixels per workgroup tile
constexpr int SP = 296;                     // Abuf row stride (bf16): 592B
// fragment-major weight layouts. A-frag mapping for mfma_f32_16x16x32_bf16:
// lane l supplies A[m = l&15][k = (l>>4)*8 + j].
constexpr int L1_FRAGS = 9 * 16 * 64;       // 9216
constexpr int L2_FRAGS = 8 * 16 * 64;       // 8192
constexpr int L3_FRAGS = 8 * 64;            // 512
constexpr int N_FRAGS = L1_FRAGS + L2_FRAGS + L3_FRAGS;   // 17920
constexpr int SC_OFF_BYTES = N_FRAGS * 16;                 // 286720
constexpr int B1EFF_OFF_BYTES = SC_OFF_BYTES + Bn * 3 * hn * wn * 4;
constexpr int FEATT_OFF_BYTES = B1EFF_OFF_BYTES + 1024;    // featT: [B][h][w][C] f32
constexpr int FRAG_BLOCKS = N_FRAGS / 256;  // 70
constexpr int SC_BLOCKS = (Bn * hn * wn) / 256;  // 72
constexpr int TP_BLOCKS = (Bn * hn * wn) / 64;   // 288 dedicated transpose blocks
}

// ---------------- prep (single dispatch): weight frags + b1eff + shortcut MLP + featT ----------------
// R8: featT transpose moved OUT of the sc-branch (its per-thread 256B stores
// were uncoalesced: 64 distinct lines per wave store) into dedicated blocks
// with LDS-staged coalesced read/write. sc-branch back to MLP-only (R0 form).
__global__ void prep_all(const float* __restrict__ w00, const float* __restrict__ w1,
                         const float* __restrict__ w2, const float* __restrict__ b00,
                         const float* __restrict__ b1,
                         const float* __restrict__ feat, const float* __restrict__ ws1,
                         const float* __restrict__ bs1, const float* __restrict__ ws2,
                         const float* __restrict__ bs2,
                         __bf16* __restrict__ wb, float* __restrict__ b1eff,
                         float* __restrict__ sc, float* __restrict__ featT)
{
    __shared__ __align__(16) float tl[64][68];   // transpose tile / b1eff cb
    const int bid = blockIdx.x;
    if (bid < FRAG_BLOCKS) {
        const int f = bid * 256 + threadIdx.x;
        bf16x8 v;
        if (f < L1_FRAGS) {
            const int k0 = f >> 10;
            const int mb = (f >> 6) & 15;
            const int l  = f & 63;
            const int m  = mb * 16 + (l & 15);
            const int kb = k0 * 32 + (l >> 4) * 8;
#pragma unroll
            for (int j = 0; j < 8; j++)
                v[j] = (kb + j < CIN) ? (__bf16)w00[m * CIN + kb + j] : (__bf16)0.f;
        } else if (f < L1_FRAGS + L2_FRAGS) {
            const int g = f - L1_FRAGS;
            const int k0 = g >> 10;
            const int mb = (g >> 6) & 15;
            const int l  = g & 63;
            const int m  = mb * 16 + (l & 15);
            const int kb = k0 * 32 + (l >> 4) * 8;
#pragma unroll
            for (int j = 0; j < 8; j++) v[j] = (__bf16)w1[m * 256 + kb + j];
        } else {
            const int g = f - (L1_FRAGS + L2_FRAGS);
            const int k0 = g >> 6;
            const int l  = g & 63;
            const int m  = l & 15;
            const int kb = k0 * 32 + (l >> 4) * 8;
#pragma unroll
            for (int j = 0; j < 8; j++)
                v[j] = (m < 3) ? (__bf16)w2[m * 256 + kb + j] : (__bf16)0.f;
        }
        *(bf16x8*)(wb + f * 8) = v;
        return;
    }
    if (bid == FRAG_BLOCKS) {
        // b1eff[o] = b1[o] + sum_c w1[o][c]*(b00[c] + 0.5*(w00[c][264]+w00[c][265]))
        float* cb = &tl[0][0];
        const int o = threadIdx.x;
        cb[o] = b00[o] + 0.5f * (w00[o * CIN + 264] + w00[o * CIN + 265]);
        __syncthreads();
        float v = b1[o];
#pragma unroll 4
        for (int k = 0; k < 256; k++) v = fmaf(w1[o * 256 + k], cb[k], v);
        b1eff[o] = v;
        return;
    }
    if (bid < FRAG_BLOCKS + 1 + SC_BLOCKS) {
        // shortcut MLP on LR grid (R0 form, no featT store)
        const int t = (bid - FRAG_BLOCKS - 1) * 256 + threadIdx.x;
        if (t >= Bn * hn * wn) return;
        const int b = t / (hn * wn);
        const int yx = t % (hn * wn);
        const float* fp = feat + b * Cn * hn * wn + yx;
        float f[Cn];
#pragma unroll
        for (int c = 0; c < Cn; c++) f[c] = fp[c * hn * wn];
        float o0 = bs2[0], o1 = bs2[1], o2 = bs2[2];
#pragma unroll 1
        for (int co = 0; co < Cn; co += 4) {
            float v0 = bs1[co], v1 = bs1[co + 1], v2 = bs1[co + 2], v3 = bs1[co + 3];
            const float* wr = ws1 + co * Cn;
#pragma unroll
            for (int ci = 0; ci < Cn; ci++) {
                const float fv = f[ci];
                v0 = fmaf(wr[ci], fv, v0);
                v1 = fmaf(wr[Cn + ci], fv, v1);
                v2 = fmaf(wr[2 * Cn + ci], fv, v2);
                v3 = fmaf(wr[3 * Cn + ci], fv, v3);
            }
            v0 = fmaxf(v0, 0.f); v1 = fmaxf(v1, 0.f); v2 = fmaxf(v2, 0.f); v3 = fmaxf(v3, 0.f);
#pragma unroll
            for (int u = 0; u < 4; u++) {
                const float vv = (u == 0) ? v0 : (u == 1) ? v1 : (u == 2) ? v2 : v3;
                o0 = fmaf(ws2[co + u], vv, o0);
                o1 = fmaf(ws2[Cn + co + u], vv, o1);
                o2 = fmaf(ws2[2 * Cn + co + u], vv, o2);
            }
        }
        sc[(b * 3 + 0) * hn * wn + yx] = o0;
        sc[(b * 3 + 1) * hn * wn + yx] = o1;
        sc[(b * 3 + 2) * hn * wn + yx] = o2;
        return;
    }
    // ---- featT transpose blocks: 64 px x 64 ch tile via LDS ----
    {
        const int tb = bid - (FRAG_BLOCKS + 1 + SC_BLOCKS);   // 0..287
        const int p0 = tb * 64;                                // global pixel
        const int bidx = p0 / (hn * wn);
        const int pp0 = p0 % (hn * wn);
        const int cr = threadIdx.x >> 2;      // channel 0..63
        const int pq = threadIdx.x & 3;       // px quarter
        const float* frow = feat + (bidx * Cn + cr) * (hn * wn) + pp0;
#pragma unroll
        for (int i = 0; i < 4; i++) {
            const int px = pq * 4 + i * 16;
            const f32x4 v = *(const f32x4*)&frow[px];
            tl[px + 0][cr] = v[0]; tl[px + 1][cr] = v[1];
            tl[px + 2][cr] = v[2]; tl[px + 3][cr] = v[3];
        }
        __syncthreads();
        const int pr = threadIdx.x >> 2;      // pixel row 0..63
        const int cq = threadIdx.x & 3;
        float* orow = featT + (p0 + pr) * Cn;
#pragma unroll
        for (int i = 0; i < 4; i++) {
            const int choff = cq * 4 + i * 16;
            *(f32x4*)&orow[choff] = *(const f32x4*)&tl[pr][choff];
        }
    }
}

__device__ __forceinline__ float gelu_fast(float x) {
    // tanh-form gelu via sigmoid in exp2 domain: x * 1/(1 + 2^(x*(d0+d1*x^2)))
    const float d0 = -2.302118074f;   // -2*0.7978845608*log2(e)
    const float d1 = -0.1029453754f;  // -2*0.0356774081*log2(e)
    float t = x * x;
    float a = x * fmaf(t, d1, d0);
    float e = __builtin_amdgcn_exp2f(a);
    return x * __builtin_amdgcn_rcpf(1.f + e);
}

__device__ __forceinline__ bf16x4 pack4(f32x4 x) {
    bf16x4 v;
    v[0] = (__bf16)x[0]; v[1] = (__bf16)x[1]; v[2] = (__bf16)x[2]; v[3] = (__bf16)x[3];
    return v;
}

// ---------------- fused main kernel (R6 structure, unchanged) ----------------
// Operand-swapped GEMMs: D = W (A-operand, global->VGPR stream) x Act^T
// (B-operand from LDS). Hot path fully scalarized (array indirection on the
// weight double-buffer defeats mem2reg -> scratch spill -> HBM blowup).
// Locked-in lessons: 16x16x32 MFMA (R1); no VGPR<=64 restructure (R3/R4
// spill); no s_setprio (R5, +9us); no cross-tile register staging (R7 spill:
// 64 staging VGPRs -> scratch, FETCH 287MB). This structure's ~84 VGPR
// operating point has NO spare registers for pipelining state.

#define MF(A, B, C) __builtin_amdgcn_mfma_f32_16x16x32_bf16((A), (B), (C), 0, 0, 0)

// 16 MFMAs of one kstep: weights W0..W3 (mblocks mb0..mb0+3) x 4 pixel-blocks
#define GSTEP(k0, W0, W1, W2, W3) do {                                          \
    const bf16x8 g0 = *(const bf16x8*)&Abuf[     lane16][(k0) * 32 + quad * 8]; \
    const bf16x8 g1 = *(const bf16x8*)&Abuf[16 + lane16][(k0) * 32 + quad * 8]; \
    const bf16x8 g2 = *(const bf16x8*)&Abuf[32 + lane16][(k0) * 32 + quad * 8]; \
    const bf16x8 g3 = *(const bf16x8*)&Abuf[48 + lane16][(k0) * 32 + quad * 8]; \
    a00 = MF(W0, g0, a00); a01 = MF(W1, g0, a01); a02 = MF(W2, g0, a02); a03 = MF(W3, g0, a03); \
    a10 = MF(W0, g1, a10); a11 = MF(W1, g1, a11); a12 = MF(W2, g1, a12); a13 = MF(W3, g1, a13); \
    a20 = MF(W0, g2, a20); a21 = MF(W1, g2, a21); a22 = MF(W2, g2, a22); a23 = MF(W3, g2, a23); \
    a30 = MF(W0, g3, a30); a31 = MF(W1, g3, a31); a32 = MF(W2, g3, a32); a33 = MF(W3, g3, a33); \
} while (0)

#define LDW(W0, W1, W2, W3, src, kk) do {             \
    W0 = (src)[((kk) * 16 + mb0 + 0) * 64 + lane];    \
    W1 = (src)[((kk) * 16 + mb0 + 1) * 64 + lane];    \
    W2 = (src)[((kk) * 16 + mb0 + 2) * 64 + lane];    \
    W3 = (src)[((kk) * 16 + mb0 + 3) * 64 + lane];    \
} while (0)

#define ZACC4(n) a##n##0 = zf; a##n##1 = zf; a##n##2 = zf; a##n##3 = zf

__global__ __launch_bounds__(256, 3) void liif_main(
    const float* __restrict__ featT, const float* __restrict__ b1eff,
    const float* __restrict__ b2v, const __bf16* __restrict__ wb,
    const float* __restrict__ sc, float* __restrict__ out)
{
    __shared__ __align__(16) __bf16 Abuf[TM][SP];

    const int t = threadIdx.x;
    const int wv = t >> 6;
    const int lane = t & 63;
    const int lane16 = lane & 15;
    const int quad = lane >> 4;
    const int mb0 = wv * 4;

    // XCD swizzle: HW assigns XCD = blockIdx % 8; remap so each XCD owns a
    // contiguous Y-band (614 KB feat slice stays L2-resident).
    constexpr int NWG = Bn * Hn * (Wn / TM);       // 4608
    const int lt = (blockIdx.x & 7) * (NWG / 8) + (blockIdx.x >> 3);
    constexpr int TPR = Wn / TM;  // 6 tiles per HR row
    const int tx = lt % TPR;
    const int Y = (lt / TPR) % Hn;
    const int b = lt / (TPR * Hn);
    const int X0 = tx * TM;

    const float cy = -1.f + 1.f / Hn + (2.f / Hn) * (float)Y;

    const bf16x8* wf1 = (const bf16x8*)wb;
    const bf16x8* wf2 = wf1 + L1_FRAGS;
    const bf16x8* w2f = wf1 + (L1_FRAGS + L2_FRAGS);

    // layer-1 initial prefetch (ksteps 0,1) issued BEFORE the gather
    bf16x8 wE0, wE1, wE2, wE3, wO0, wO1, wO2, wO3;
    LDW(wE0, wE1, wE2, wE3, wf1, 0);
    LDW(wO0, wO1, wO2, wO3, wf1, 1);

    // ---------- phase 1: build grid features [64 x 266] bf16 in Abuf ----------
    {
        const int p = lane;     // pixel in tile
        const int j = wv;       // this wave handles corner j's gather
        const int X = X0 + p;
        const float cx = -1.f + 1.f / Wn + (2.f / Wn) * (float)X;
        // dedupe: only 2 distinct y-variants (c&2) and 2 x-variants (c&1)
        float relyv[2], relxv[2];
        int iyy[2], ixx[2];
#pragma unroll
        for (int c2 = 0; c2 < 2; c2++) {
            const float v = c2 ? 1.f : -1.f;
            float sy = fminf(fmaxf(cy + v * (1.f / hn) + 1e-6f, -1.f + 1e-6f), 1.f - 1e-6f);
            float uy = ((sy + 1.f) * hn - 1.f) * 0.5f;
            int iy = min(max((int)rintf(uy), 0), hn - 1);   // round-half-even == jnp.round
            float oy = -1.f + 1.f / hn + (2.f / hn) * (float)iy;
            relyv[c2] = (cy - oy) * hn; iyy[c2] = iy;
            float sx = fminf(fmaxf(cx + v * (1.f / wn) + 1e-6f, -1.f + 1e-6f), 1.f - 1e-6f);
            float ux = ((sx + 1.f) * wn - 1.f) * 0.5f;
            int ix = min(max((int)rintf(ux), 0), wn - 1);
            float ox = -1.f + 1.f / wn + (2.f / wn) * (float)ix;
            relxv[c2] = (cx - ox) * wn; ixx[c2] = ix;
        }
        // corner c: vx = (c&2)?+1:-1 (height), vy = (c&1)?+1:-1 (width)
        float area[4];
#pragma unroll
        for (int c = 0; c < 4; c++)
            area[c] = fabsf(relyv[(c >> 1) & 1] * relxv[c & 1]) + 1e-9f;
        const float tot = area[0] + area[1] + area[2] + area[3];
        const float wj = area[3 - j] / tot;   // LIIF area swap 0<->3, 1<->2

        if (j == 0) {  // channels 0..7: [rel_y0, rel_x0, ..., rel_y3, rel_x3]
            bf16x8 v;
#pragma unroll
            for (int c = 0; c < 4; c++) {
                v[2 * c] = (__bf16)relyv[(c >> 1) & 1];
                v[2 * c + 1] = (__bf16)relxv[c & 1];
            }
            *(bf16x8*)&Abuf[p][0] = v;
        }
        // channels 8+64j .. 8+64j+63: feat at (iy_j, ix_j) scaled by wj
        // featT is channel-last: 64 consecutive f32 -> 16 dwordx4 loads
        const float* fb = featT + ((b * hn + iyy[(j >> 1) & 1]) * wn + ixx[j & 1]) * Cn;
#pragma unroll
        for (int c8 = 0; c8 < 8; c8++) {
            const f32x4 u0 = *(const f32x4*)&fb[c8 * 8];
            const f32x4 u1 = *(const f32x4*)&fb[c8 * 8 + 4];
            bf16x8 v;
            v[0] = (__bf16)(u0[0] * wj); v[1] = (__bf16)(u0[1] * wj);
            v[2] = (__bf16)(u0[2] * wj); v[3] = (__bf16)(u0[3] * wj);
            v[4] = (__bf16)(u1[0] * wj); v[5] = (__bf16)(u1[1] * wj);
            v[6] = (__bf16)(u1[2] * wj); v[7] = (__bf16)(u1[3] * wj);
            *(bf16x8*)&Abuf[p][8 + 64 * j + c8 * 8] = v;
        }
        if (j == 3) {  // channels 264..287 zero (rel_cell folded into b1eff)
            bf16x8 z;
#pragma unroll
            for (int cc = 0; cc < 8; cc++) z[cc] = (__bf16)0.f;
            *(bf16x8*)&Abuf[p][264] = z;
            *(bf16x8*)&Abuf[p][272] = z;
            *(bf16x8*)&Abuf[p][280] = z;
        }
    }
    __syncthreads();

    const f32x4 zf = (f32x4){0.f, 0.f, 0.f, 0.f};
    f32x4 a00, a01, a02, a03, a10, a11, a12, a13;
    f32x4 a20, a21, a22, a23, a30, a31, a32, a33;
    ZACC4(0); ZACC4(1); ZACC4(2); ZACC4(3);

    // ---------- layer 1: W00[256x288] x G^T, 9 ksteps ----------
    GSTEP(0, wE0, wE1, wE2, wE3); LDW(wE0, wE1, wE2, wE3, wf1, 2);
    GSTEP(1, wO0, wO1, wO2, wO3); LDW(wO0, wO1, wO2, wO3, wf1, 3);
    GSTEP(2, wE0, wE1, wE2, wE3); LDW(wE0, wE1, wE2, wE3, wf1, 4);
    GSTEP(3, wO0, wO1, wO2, wO3); LDW(wO0, wO1, wO2, wO3, wf1, 5);
    GSTEP(4, wE0, wE1, wE2, wE3); LDW(wE0, wE1, wE2, wE3, wf1, 6);
    GSTEP(5, wO0, wO1, wO2, wO3); LDW(wO0, wO1, wO2, wO3, wf1, 7);
    GSTEP(6, wE0, wE1, wE2, wE3); LDW(wE0, wE1, wE2, wE3, wf1, 8);
    GSTEP(7, wO0, wO1, wO2, wO3); LDW(wO0, wO1, wO2, wO3, wf2, 0);  // next layer k0
    GSTEP(8, wE0, wE1, wE2, wE3); LDW(wE0, wE1, wE2, wE3, wf2, 1);  // next layer k1

    __syncthreads();  // all grid readers done before overwriting Abuf with X
    // epilogue 1: no bias (b00 + rel_cell folded into b1eff); packed b64 writes
    {
        const int ch0 = mb0 * 16 + quad * 4;
        *(bf16x4*)&Abuf[     lane16][ch0     ] = pack4(a00);
        *(bf16x4*)&Abuf[16 + lane16][ch0     ] = pack4(a10);
        *(bf16x4*)&Abuf[32 + lane16][ch0     ] = pack4(a20);
        *(bf16x4*)&Abuf[48 + lane16][ch0     ] = pack4(a30);
        *(bf16x4*)&Abuf[     lane16][ch0 + 16] = pack4(a01);
        *(bf16x4*)&Abuf[16 + lane16][ch0 + 16] = pack4(a11);
        *(bf16x4*)&Abuf[32 + lane16][ch0 + 16] = pack4(a21);
        *(bf16x4*)&Abuf[48 + lane16][ch0 + 16] = pack4(a31);
        *(bf16x4*)&Abuf[     lane16][ch0 + 32] = pack4(a02);
        *(bf16x4*)&Abuf[16 + lane16][ch0 + 32] = pack4(a12);
        *(bf16x4*)&Abuf[32 + lane16][ch0 + 32] = pack4(a22);
        *(bf16x4*)&Abuf[48 + lane16][ch0 + 32] = pack4(a32);
        *(bf16x4*)&Abuf[     lane16][ch0 + 48] = pack4(a03);
        *(bf16x4*)&Abuf[16 + lane16][ch0 + 48] = pack4(a13);
        *(bf16x4*)&Abuf[32 + lane16][ch0 + 48] = pack4(a23);
        *(bf16x4*)&Abuf[48 + lane16][ch0 + 48] = pack4(a33);
    }
    __syncthreads();

    ZACC4(0); ZACC4(1); ZACC4(2); ZACC4(3);

    // ---------- layer 2: W1[256x256] x X, 8 ksteps (k0 in wO, k1 in wE) ----------
    GSTEP(0, wO0, wO1, wO2, wO3); LDW(wO0, wO1, wO2, wO3, wf2, 2);
    GSTEP(1, wE0, wE1, wE2, wE3); LDW(wE0, wE1, wE2, wE3, wf2, 3);
    GSTEP(2, wO0, wO1, wO2, wO3); LDW(wO0, wO1, wO2, wO3, wf2, 4);
    GSTEP(3, wE0, wE1, wE2, wE3); LDW(wE0, wE1, wE2, wE3, wf2, 5);
    GSTEP(4, wO0, wO1, wO2, wO3); LDW(wO0, wO1, wO2, wO3, wf2, 6);
    GSTEP(5, wE0, wE1, wE2, wE3); LDW(wE0, wE1, wE2, wE3, wf2, 7);
    GSTEP(6, wO0, wO1, wO2, wO3); wO0 = w2f[0 * 64 + lane];          // w2 k0
    GSTEP(7, wE0, wE1, wE2, wE3); wE0 = w2f[1 * 64 + lane];          // w2 k1

    __syncthreads();
    // epilogue 2: bias + gelu, packed b64 writes
    {
        const int ch0 = mb0 * 16 + quad * 4;
        const f32x4 bi0 = *(const f32x4*)&b1eff[ch0];
        const f32x4 bi1 = *(const f32x4*)&b1eff[ch0 + 16];
        const f32x4 bi2 = *(const f32x4*)&b1eff[ch0 + 32];
        const f32x4 bi3 = *(const f32x4*)&b1eff[ch0 + 48];
#define GEL4(x, bi) { bf16x4 v; v[0] = (__bf16)gelu_fast((x)[0] + (bi)[0]); \
        v[1] = (__bf16)gelu_fast((x)[1] + (bi)[1]); \
        v[2] = (__bf16)gelu_fast((x)[2] + (bi)[2]); \
        v[3] = (__bf16)gelu_fast((x)[3] + (bi)[3]); vv = v; }
        bf16x4 vv;
        GEL4(a00, bi0); *(bf16x4*)&Abuf[     lane16][ch0     ] = vv;
        GEL4(a10, bi0); *(bf16x4*)&Abuf[16 + lane16][ch0     ] = vv;
        GEL4(a20, bi0); *(bf16x4*)&Abuf[32 + lane16][ch0     ] = vv;
        GEL4(a30, bi0); *(bf16x4*)&Abuf[48 + lane16][ch0     ] = vv;
        GEL4(a01, bi1); *(bf16x4*)&Abuf[     lane16][ch0 + 16] = vv;
        GEL4(a11, bi1); *(bf16x4*)&Abuf[16 + lane16][ch0 + 16] = vv;
        GEL4(a21, bi1); *(bf16x4*)&Abuf[32 + lane16][ch0 + 16] = vv;
        GEL4(a31, bi1); *(bf16x4*)&Abuf[48 + lane16][ch0 + 16] = vv;
        GEL4(a02, bi2); *(bf16x4*)&Abuf[     lane16][ch0 + 32] = vv;
        GEL4(a12, bi2); *(bf16x4*)&Abuf[16 + lane16][ch0 + 32] = vv;
        GEL4(a22, bi2); *(bf16x4*)&Abuf[32 + lane16][ch0 + 32] = vv;
        GEL4(a32, bi2); *(bf16x4*)&Abuf[48 + lane16][ch0 + 32] = vv;
        GEL4(a03, bi3); *(bf16x4*)&Abuf[     lane16][ch0 + 48] = vv;
        GEL4(a13, bi3); *(bf16x4*)&Abuf[16 + lane16][ch0 + 48] = vv;
        GEL4(a23, bi3); *(bf16x4*)&Abuf[32 + lane16][ch0 + 48] = vv;
        GEL4(a33, bi3); *(bf16x4*)&Abuf[48 + lane16][ch0 + 48] = vv;
#undef GEL4
    }
    __syncthreads();

    // ---------- layer 3: W2[16x256] x Y, 8 ksteps; wave wv owns pixel-block wv ----------
    f32x4 acc3 = zf;
#define YF(k0) (*(const bf16x8*)&Abuf[wv * 16 + lane16][(k0) * 32 + quad * 8])
    acc3 = MF(wO0, YF(0), acc3); wO0 = w2f[2 * 64 + lane];
    acc3 = MF(wE0, YF(1), acc3); wE0 = w2f[3 * 64 + lane];
    acc3 = MF(wO0, YF(2), acc3); wO0 = w2f[4 * 64 + lane];
    acc3 = MF(wE0, YF(3), acc3); wE0 = w2f[5 * 64 + lane];
    acc3 = MF(wO0, YF(4), acc3); wO0 = w2f[6 * 64 + lane];
    acc3 = MF(wE0, YF(5), acc3); wE0 = w2f[7 * 64 + lane];
    acc3 = MF(wO0, YF(6), acc3);
    acc3 = MF(wE0, YF(7), acc3);
#undef YF

    // ---------- epilogue: rows 0..2 (quad 0) hold the 3 output channels ----------
    if (quad == 0) {
        const int pix = wv * 16 + lane16;
        const int X = X0 + pix;
        const float uy = ((cy + 1.f) * hn - 1.f) * 0.5f;
        const float fy = floorf(uy);
        const float wy = uy - fy;
        const int y0i = min(max((int)fy, 0), hn - 1);
        const int y1i = min(max((int)fy + 1, 0), hn - 1);
        const float cx = -1.f + 1.f / Wn + (2.f / Wn) * (float)X;
        const float ux = ((cx + 1.f) * wn - 1.f) * 0.5f;
        const float fx = floorf(ux);
        const float wx = ux - fx;
        const int x0i = min(max((int)fx, 0), wn - 1);
        const int x1i = min(max((int)fx + 1, 0), wn - 1);
        const float w00b = (1.f - wy) * (1.f - wx), w01b = (1.f - wy) * wx;
        const float w10b = wy * (1.f - wx), w11b = wy * wx;
#pragma unroll
        for (int r = 0; r < 3; r++) {
            const float* scb = sc + (b * 3 + r) * (hn * wn);
            const float samp = scb[y0i * wn + x0i] * w00b + scb[y0i * wn + x1i] * w01b
                             + scb[y1i * wn + x0i] * w10b + scb[y1i * wn + x1i] * w11b;
            out[((b * 3 + r) * Hn + Y) * Wn + X] = acc3[r] + b2v[r] + samp;
        }
    }
}

extern "C" void kernel_launch(void* const* d_in, const int* in_sizes, int n_in,
                              void* d_out, int out_size, void* d_ws, size_t ws_size,
                              hipStream_t stream)
{
    const float* feat = (const float*)d_in[0];
    const float* w00  = (const float*)d_in[1];
    const float* b00  = (const float*)d_in[2];
    const float* w1   = (const float*)d_in[3];
    const float* b1   = (const float*)d_in[4];
    const float* w2   = (const float*)d_in[5];
    const float* b2   = (const float*)d_in[6];
    const float* ws1  = (const float*)d_in[7];
    const float* bs1  = (const float*)d_in[8];
    const float* ws2  = (const float*)d_in[9];
    const float* bs2  = (const float*)d_in[10];
    float* out = (float*)d_out;

    __bf16* wb    = (__bf16*)d_ws;
    float* scbuf  = (float*)((char*)d_ws + SC_OFF_BYTES);
    float* b1eff  = (float*)((char*)d_ws + B1EFF_OFF_BYTES);
    float* featT  = (float*)((char*)d_ws + FEATT_OFF_BYTES);

    prep_all<<<FRAG_BLOCKS + 1 + SC_BLOCKS + TP_BLOCKS, 256, 0, stream>>>(
        w00, w1, w2, b00, b1, feat, ws1, bs1, ws2, bs2, wb, b1eff, scbuf, featT);
    liif_main<<<Bn * Hn * (Wn / TM), 256, 0, stream>>>(featT, b1eff, b2, wb, scbuf, out);
}